// Round 10
// baseline (1331.038 us; speedup 1.0000x reference)
//
#include <hip/hip_runtime.h>
#include <math.h>

#define N_TOK 131072
#define VOCAB 50257
#define DIM   512
#define K_CON 512
#define NPARTS 12565   // ceil(VOCAB/4)

// d_out layout (float32 elements)
#define OFF_ENC  ((size_t)0)
#define OFF_QW   ((size_t)67108864)
#define OFF_DOCU ((size_t)134217728)
#define OFF_OUT  ((size_t)134218240)
#define OFF_VQ   ((size_t)134268497)
#define OFF_LTS  ((size_t)134268498)

// ws layout (bytes)
#define WS_COUNTS 0        // 512 * u32
#define WS_VQ     2048     // double
#define WS_LTS    2056     // double
#define WS_SUMV   2072     // double
#define WS_NFLAG  2080     // u32
#define WS_NARR   4096     // 512 f32
#define WS_SARR   6144     // 512 f32
#define WS_BINC   8192     // VOCAB u32
#define WS_LOGITS 209920   // VOCAB f32 (holds exp(logit))
#define WS_FLAGS  411648   // FLAG_CAP u32  (ends 542720)
#define WS_PART   544768   // NPARTS double (ends 645288)
#define FLAG_CAP  32768

typedef __attribute__((ext_vector_type(4)))  float f32x4;
typedef __attribute__((ext_vector_type(8)))  _Float16 f16x8;
typedef __attribute__((ext_vector_type(16))) float f32x16;

// Codebook as fp16 of (512*c), MFMA fragment layout:
// frag index (s, hf, c): [(s*2+hf)*512 + c] x f16x8 ; s = K-step (16 dims),
// hf selects dims s*16+hf*8..+7, c = concept.  512 KB total, L2-resident.
__device__ _Float16 g_B1[32 * 2 * 512 * 8];

__device__ __forceinline__ f16x8 cvt8(const float4 a0, const float4 a1) {
    f16x8 h;
    h[0] = (_Float16)a0.x; h[1] = (_Float16)a0.y;
    h[2] = (_Float16)a0.z; h[3] = (_Float16)a0.w;
    h[4] = (_Float16)a1.x; h[5] = (_Float16)a1.y;
    h[6] = (_Float16)a1.z; h[7] = (_Float16)a1.w;
    return h;
}

// ---------------------------------------------------------------------------
// merged: n/s arrays + codebook fp16 (512*c) prep
__global__ void k_nsprep(const float* __restrict__ cw, float* __restrict__ n_arr,
                         float* __restrict__ s_arr, _Float16* __restrict__ b1) {
    int w = threadIdx.x >> 6, lane = threadIdx.x & 63;
    int r = blockIdx.x * 4 + w;
    const float* row = cw + (size_t)r * DIM;
    {
        float4 a = *(const float4*)(row + lane * 8);
        float4 b = *(const float4*)(row + lane * 8 + 4);
        float v[8] = {a.x,a.y,a.z,a.w,b.x,b.y,b.z,b.w};
        double na = 0.0, sa = 0.0;
        #pragma unroll
        for (int e = 0; e < 8; ++e) { na += (double)v[e]*v[e]; sa += (double)v[e]; }
        for (int off = 32; off; off >>= 1) {
            na += __shfl_down(na, off);
            sa += __shfl_down(sa, off);
        }
        if (lane == 0) { n_arr[r] = (float)na; s_arr[r] = (float)sa; }
    }
    {
        int s = lane >> 1, hf = lane & 1;
        const float* p = row + s * 16 + hf * 8;
        float4 xa = *(const float4*)p;
        float4 xb = *(const float4*)(p + 4);
        float xf[8] = {xa.x,xa.y,xa.z,xa.w,xb.x,xb.y,xb.z,xb.w};
        f16x8 h8;
        #pragma unroll
        for (int e = 0; e < 8; ++e) h8[e] = (_Float16)(xf[e] * 512.0f);
        *(f16x8*)&b1[(((size_t)s * 2 + hf) * 512 + r) * 8] = h8;
    }
}

// ---------------------------------------------------------------------------
// Main: fp16 single-term MFMA distance GEMM, BARRIER-FREE K-loop.
// 256 threads = 4 waves; wave wv owns concepts wv*128..+127 for ALL 64
// tokens (acc0=tokens 0-31, acc1=32-63; 128 AGPRs). B fragments are loaded
// per-wave straight from L2-resident g_B1 into registers, double-buffered,
// software-pipelined one step ahead. No LDS staging, no K-loop barriers.
// ARCH-VGPR NOTE: fp16 single-term needs bA/bB(32)+aA/aB(32)+frags(16)+addr
// ~= 110 arch regs <= 128 at 2 waves/SIMD. (bf16 3-term version of this
// structure spilled in round 4 — fp16 is why it fits now.)
__global__ __launch_bounds__(256, 2)
void k_main(const int* __restrict__ doc, const float* __restrict__ emb,
            const float* __restrict__ cw, const float* __restrict__ n_arr,
            float* __restrict__ out, unsigned* __restrict__ counts,
            unsigned* __restrict__ binc,
            double* __restrict__ vq_acc, unsigned* __restrict__ nflag,
            unsigned* __restrict__ flag_list) {
    __shared__ float nsl[512];
    __shared__ float nxs[64];
    __shared__ uint4 redv[4][64];
    __shared__ int docs[64];
    __shared__ int idxs[64];
    __shared__ double dred[256];

    const int tid   = threadIdx.x;
    const int n0    = blockIdx.x * 64;
    const int lane  = tid & 63;
    const int wv    = tid >> 6;
    const int hv    = lane >> 5;
    const int ln31  = lane & 31;
    const int cbase = wv * 128 + ln31;

    if (tid < 64) docs[tid] = doc[n0 + tid];
    nsl[tid]       = n_arr[tid];
    nsl[tid + 256] = n_arr[tid + 256];
    __syncthreads();

    // nx pre-pass: 4 threads per token, double partials (also warms L3/L2)
    {
        int t = tid >> 2, q = tid & 3;
        const float* xr = emb + (size_t)docs[t] * DIM + q * 128;
        double px = 0.0;
        for (int f = 0; f < 32; ++f) {
            float4 v = *(const float4*)(xr + f * 4);
            px += (double)v.x*v.x + (double)v.y*v.y + (double)v.z*v.z + (double)v.w*v.w;
        }
        dred[tid] = px;
    }
    __syncthreads();
    if (tid < 64)
        nxs[tid] = (float)(dred[tid*4] + dred[tid*4+1] + dred[tid*4+2] + dred[tid*4+3]);

    const float* xr0 = emb + (size_t)docs[ln31] * DIM;
    const float* xr1 = emb + (size_t)docs[ln31 + 32] * DIM;
    const f16x8* bt = (const f16x8*)g_B1;

    f32x16 acc0[4], acc1[4];
    #pragma unroll
    for (int n = 0; n < 4; ++n) { acc0[n] = (f32x16)(0.0f); acc1[n] = (f32x16)(0.0f); }

    f16x8 bA[4], bB[4];       // B frags, shared by both token-groups
    float4 aA[4], aB[4];      // A raw: 2 tokens x 8 dims
    f16x8 fA0, fA1, fB0, fB1; // converted A frags

#define LOAD_B(S, B)                                                          \
    _Pragma("unroll")                                                         \
    for (int n = 0; n < 4; ++n)                                               \
        (B)[n] = bt[((size_t)(S) * 2 + hv) * 512 + cbase + n * 32];
#define LOAD_A(S, A)                                                          \
    {                                                                         \
        const float* p0 = xr0 + (S) * 16 + hv * 8;                            \
        const float* p1 = xr1 + (S) * 16 + hv * 8;                            \
        (A)[0] = *(const float4*)p0; (A)[1] = *(const float4*)(p0 + 4);       \
        (A)[2] = *(const float4*)p1; (A)[3] = *(const float4*)(p1 + 4);       \
    }
#define MFMA8(F0, F1, B)                                                      \
    _Pragma("unroll")                                                         \
    for (int n = 0; n < 4; ++n) {                                             \
        acc0[n] = __builtin_amdgcn_mfma_f32_32x32x16_f16((F0), (B)[n], acc0[n], 0, 0, 0); \
        acc1[n] = __builtin_amdgcn_mfma_f32_32x32x16_f16((F1), (B)[n], acc1[n], 0, 0, 0); \
    }

    LOAD_B(0, bA); LOAD_A(0, aA);
    LOAD_B(1, bB); LOAD_A(1, aB);
    fA0 = cvt8(aA[0], aA[1]); fA1 = cvt8(aA[2], aA[3]);

    #pragma unroll 1
    for (int s = 0; s < 30; s += 2) {
        MFMA8(fA0, fA1, bA);
        fB0 = cvt8(aB[0], aB[1]); fB1 = cvt8(aB[2], aB[3]);
        LOAD_B(s + 2, bA); LOAD_A(s + 2, aA);
        MFMA8(fB0, fB1, bB);
        fA0 = cvt8(aA[0], aA[1]); fA1 = cvt8(aA[2], aA[3]);
        LOAD_B(s + 3, bB); LOAD_A(s + 3, aB);
    }
    MFMA8(fA0, fA1, bA);
    fB0 = cvt8(aB[0], aB[1]); fB1 = cvt8(aB[2], aB[3]);
    MFMA8(fB0, fB1, bB);

#undef MFMA8
#undef LOAD_A
#undef LOAD_B

    float nsv[4];
    #pragma unroll
    for (int n = 0; n < 4; ++n) nsv[n] = nsl[cbase + n * 32];

    // per-row argmin + second best; C/D: col=lane&31, row=(r&3)+8*(r>>2)+4*hv
    // acc holds S = x_h . (512 c)_h ; d = fmaf(-2^-8, S, nx+nc)
    #pragma unroll
    for (int m = 0; m < 2; ++m) {
        const f32x16* am = m ? acc1 : acc0;
        #pragma unroll
        for (int r = 0; r < 16; ++r) {
            int tt = (r & 3) + ((r >> 2) << 3) + (hv << 2);   // 0..31
            float nxr = nxs[m * 32 + tt];
            float v1 = INFINITY, v2 = INFINITY; int j1 = 0x7fffffff;
            #pragma unroll
            for (int n = 0; n < 4; ++n) {
                float d = fmaf(-0.00390625f, am[n][r], nxr + nsv[n]);
                int jj = cbase + n * 32;
                if (d < v1) { v2 = v1; v1 = d; j1 = jj; }
                else if (d < v2) { v2 = d; }
            }
            #pragma unroll
            for (int off = 1; off < 32; off <<= 1) {
                float ov1 = __shfl_xor(v1, off);
                int   oj1 = __shfl_xor(j1, off);
                float ov2 = __shfl_xor(v2, off);
                v2 = fminf(fminf(v2, ov2), fmaxf(v1, ov1));
                bool take = (ov1 < v1) || (ov1 == v1 && oj1 < j1);
                if (take) { v1 = ov1; j1 = oj1; }
            }
            if (ln31 == 0)
                redv[wv][m * 32 + tt] = make_uint4(__float_as_uint(v1), (unsigned)j1,
                                                   __float_as_uint(v2), 0u);
        }
    }
    __syncthreads();
    double myv1 = 0.0;
    if (tid < 64) {
        uint4 a = redv[0][tid];
        float v1 = __uint_as_float(a.x), v2 = __uint_as_float(a.z);
        int j1 = (int)a.y;
        #pragma unroll
        for (int w = 1; w < 4; ++w) {
            uint4 b = redv[w][tid];
            float wv1 = __uint_as_float(b.x), wv2 = __uint_as_float(b.z);
            v2 = fminf(fminf(v2, wv2), fmaxf(v1, wv1));
            bool take = (wv1 < v1) || (wv1 == v1 && (int)b.y < j1);
            if (take) { v1 = wv1; j1 = (int)b.y; }
        }
        idxs[tid] = j1;
        atomicAdd(&counts[j1], 1u);
        atomicAdd(&binc[docs[tid]], 1u);
        myv1 = (double)v1;
        if (v2 - v1 <= 2e-6f) {           // ~8 sigma of fp16-path noise
            unsigned pq = atomicAdd(nflag, 1u);
            if (pq < FLAG_CAP) flag_list[pq] = (unsigned)(n0 + tid);
        }
    }
    dred[tid] = myv1;
    __syncthreads();

    // encodings: one-hot rows (nontemporal streaming output)
    for (int lin = tid; lin < 8192; lin += 256) {
        int t = lin >> 7, f4 = lin & 127;
        int idx = idxs[t];
        int b4 = f4 << 2;
        f32x4 v;
        v.x = (idx == b4)     ? 1.f : 0.f;
        v.y = (idx == b4 + 1) ? 1.f : 0.f;
        v.z = (idx == b4 + 2) ? 1.f : 0.f;
        v.w = (idx == b4 + 3) ? 1.f : 0.f;
        __builtin_nontemporal_store(v,
            (f32x4*)(out + OFF_ENC + ((size_t)(n0 + t) << 9) + (size_t)b4));
    }
    // quantized_words = codebook rows
    for (int lin = tid; lin < 8192; lin += 256) {
        int t = lin >> 7, f4 = lin & 127;
        f32x4 c4 = *(const f32x4*)(cw + (size_t)idxs[t] * DIM + (f4 << 2));
        __builtin_nontemporal_store(c4,
            (f32x4*)(out + OFF_QW + ((size_t)(n0 + t) << 9) + (size_t)(f4 << 2)));
    }
    // vq partial reduce (flagged tokens patched exactly by k_fixup)
    for (int st = 128; st; st >>= 1) {
        if (tid < st) dred[tid] += dred[tid + st];
        __syncthreads();
    }
    if (tid == 0) atomicAdd(vq_acc, dred[0]);
}

// ---------------------------------------------------------------------------
// Exact fp32 recompute for flagged near-tie tokens (vectorized, grid-stride).
__global__ __launch_bounds__(512)
void k_fixup(const int* __restrict__ doc, const float* __restrict__ emb,
             const float* __restrict__ cw, const float* __restrict__ n_arr,
             const unsigned* __restrict__ nflag, const unsigned* __restrict__ flag_list,
             float* __restrict__ out, unsigned* __restrict__ counts,
             double* __restrict__ vq_acc) {
    __shared__ float4 xs4[128];
    __shared__ double dr[128];
    __shared__ float nxf_sh;
    __shared__ int oldj_sh;
    __shared__ float vsh[512];
    __shared__ unsigned long long keys[512];

    const int tid = threadIdx.x;
    unsigned nf = *nflag;
    if (nf > FLAG_CAP) nf = FLAG_CAP;

    for (unsigned f = blockIdx.x; f < nf; f += gridDim.x) {
        int t = (int)flag_list[f];
        int dc = doc[t];
        if (tid < 128) {
            float4 v = *(const float4*)(emb + (size_t)dc * DIM + tid * 4);
            xs4[tid] = v;
            dr[tid] = (double)v.x*v.x + (double)v.y*v.y
                    + (double)v.z*v.z + (double)v.w*v.w;
        }
        if (tid == 0) oldj_sh = -1;
        __syncthreads();
        for (int st = 64; st; st >>= 1) {
            if (tid < st) dr[tid] += dr[tid + st];
            __syncthreads();
        }
        if (tid == 0) nxf_sh = (float)dr[0];
        {
            float e = out[OFF_ENC + (size_t)t * 512 + tid];
            if (e == 1.0f) oldj_sh = tid;
        }
        __syncthreads();
        {
            const float4* cr = (const float4*)(cw + (size_t)tid * DIM);
            float acc = 0.f;
            #pragma unroll 8
            for (int fq = 0; fq < 128; ++fq) {
                float4 c4 = cr[fq], x4 = xs4[fq];
                acc = fmaf(x4.x, c4.x, acc);
                acc = fmaf(x4.y, c4.y, acc);
                acc = fmaf(x4.z, c4.z, acc);
                acc = fmaf(x4.w, c4.w, acc);
            }
            float v = fmaf(-2.f, acc, nxf_sh + n_arr[tid]);
            vsh[tid] = v;
            keys[tid] = (((unsigned long long)__float_as_uint(v)) << 32) | (unsigned)tid;
        }
        __syncthreads();
        for (int st = 256; st; st >>= 1) {
            if (tid < st) {
                unsigned long long o = keys[tid + st];
                if (o < keys[tid]) keys[tid] = o;
            }
            __syncthreads();
        }
        int newj = (int)(keys[0] & 0xffffffffu);
        int oldj = oldj_sh;
        if (newj != oldj) {
            if (tid == 0) {
                out[OFF_ENC + (size_t)t * 512 + oldj] = 0.0f;
                out[OFF_ENC + (size_t)t * 512 + newj] = 1.0f;
                atomicSub(&counts[oldj], 1u);
                atomicAdd(&counts[newj], 1u);
                atomicAdd(vq_acc, (double)vsh[newj] - (double)vsh[oldj]);
            }
            if (tid < 128) {
                float4 cn = *(const float4*)(cw + (size_t)newj * DIM + tid * 4);
                *(float4*)&out[OFF_QW + (size_t)t * 512 + tid * 4] = cn;
            }
        }
        __syncthreads();
    }
}

// ---------------------------------------------------------------------------
__global__ void k_docu(const unsigned* __restrict__ counts,
                       const float* __restrict__ cw, float* __restrict__ out_docu) {
    __shared__ float cnt[512];
    int tid = threadIdx.x;
    cnt[tid] = (float)counts[tid];
    __syncthreads();
    double a = 0.0;
    for (int j = 0; j < K_CON; ++j)
        a += (double)cnt[j] * (double)cw[(size_t)j * DIM + tid];
    out_docu[tid] = (float)(a * (1.0 / (double)N_TOK));
}

__global__ __launch_bounds__(256)
void k_lts(const float* __restrict__ cw, const float* __restrict__ n_arr,
           const float* __restrict__ s_arr, double* __restrict__ lts_acc) {
    __shared__ float ci[4 * 512];
    __shared__ float cjs[64 * 68];
    __shared__ double dred[256];
    const int tid = threadIdx.x;
    const int i0 = blockIdx.x * 4;
    #pragma unroll
    for (int rep = 0; rep < 2; ++rep) {
        int lin = rep * 256 + tid;
        int r = lin >> 7, fq = lin & 127;
        *(float4*)&ci[r*512 + fq*4] = *(const float4*)(cw + (size_t)(i0+r)*DIM + fq*4);
    }
    const int jj = tid & 63, ih = tid >> 6;
    const int ig = i0 + ih;
    const float ni = n_arr[ig], si = s_arr[ig];
    const float EPS = 1e-6f;
    double lsum = 0.0;
    for (int jc = 0; jc < 8; ++jc) {
        float accv = 0.f;
        for (int dc = 0; dc < 8; ++dc) {
            __syncthreads();
            #pragma unroll
            for (int rep = 0; rep < 4; ++rep) {
                int lin = rep * 256 + tid;
                int j = lin >> 4, fq = lin & 15;
                float4 v = *(const float4*)(cw + (size_t)(jc*64 + j)*DIM + dc*64 + fq*4);
                cjs[(fq*4+0)*68 + j] = v.x; cjs[(fq*4+1)*68 + j] = v.y;
                cjs[(fq*4+2)*68 + j] = v.z; cjs[(fq*4+3)*68 + j] = v.w;
            }
            __syncthreads();
            #pragma unroll 4
            for (int d = 0; d < 64; ++d)
                accv = fmaf(ci[ih*512 + dc*64 + d], cjs[d*68 + jj], accv);
        }
        int jg = jc*64 + jj;
        float ddv = ni + n_arr[jg] - 2.f*accv + 2.f*EPS*(si - s_arr[jg]) + 512.f*EPS*EPS;
        float dist = sqrtf(fmaxf(ddv, 0.f));
        lsum += (double)((ig == jg) ? dist : fmaxf(0.f, 1.f - dist));
    }
    dred[tid] = lsum;
    __syncthreads();
    for (int s = 128; s; s >>= 1) {
        if (tid < s) dred[tid] += dred[tid + s];
        __syncthreads();
    }
    if (tid == 0) atomicAdd(lts_acc, dred[0]);
}

// logits -> e = exp(logit + bias), per-block partial sums (no max: |logit| tiny)
__global__ void k_logexp(const float* __restrict__ docu, const float* __restrict__ q2w,
                         const float* __restrict__ q2b, float* __restrict__ evals,
                         double* __restrict__ parts) {
    __shared__ double esh[4];
    int wvi = threadIdx.x >> 6, lane = threadIdx.x & 63;
    int v = blockIdx.x * 4 + wvi;
    if (lane == 0) esh[wvi] = 0.0;
    if (v < VOCAB) {
        const float* wr = q2w + (size_t)v * DIM;
        float4 a = *(const float4*)(wr + lane*8);
        float4 b = *(const float4*)(wr + lane*8 + 4);
        float4 da = *(const float4*)(docu + lane*8);
        float4 db = *(const float4*)(docu + lane*8 + 4);
        float p = a.x*da.x + a.y*da.y + a.z*da.z + a.w*da.w
                + b.x*db.x + b.y*db.y + b.z*db.z + b.w*db.w;
        for (int off = 32; off; off >>= 1) p += __shfl_down(p, off);
        if (lane == 0) {
            float e = expf(p + q2b[v]);
            evals[v] = e;
            esh[wvi] = (double)e;
        }
    }
    __syncthreads();
    if (threadIdx.x == 0)
        parts[blockIdx.x] = esh[0] + esh[1] + esh[2] + esh[3];
}

__global__ void k_sumred(const double* __restrict__ parts, double* __restrict__ sumv) {
    __shared__ double red[256];
    int tid = threadIdx.x;
    double s = 0.0;
    for (int i = tid; i < NPARTS; i += 256) s += parts[i];
    red[tid] = s; __syncthreads();
    for (int st = 128; st; st >>= 1) {
        if (tid < st) red[tid] += red[tid + st];
        __syncthreads();
    }
    if (tid == 0) *sumv = red[0];
}

__global__ void k_final(const float* __restrict__ evals,
                        const double* __restrict__ sumv, const unsigned* __restrict__ binc,
                        const double* __restrict__ vq_acc, const double* __restrict__ lts_acc,
                        float* __restrict__ out) {
    int v = blockIdx.x * 256 + threadIdx.x;
    if (v < VOCAB) {
        float s = (float)(*sumv);
        float p = evals[v] / s;
        out[OFF_OUT + v] = logf(p + 1e-6f) * (float)binc[v];
    }
    if (v == 0) {
        out[OFF_VQ]  = (float)(1.25 * (*vq_acc) * (1.0 / 67108864.0));
        out[OFF_LTS] = (float)((*lts_acc) * (1.0 / 262144.0));
    }
}

// ---------------------------------------------------------------------------
extern "C" void kernel_launch(void* const* d_in, const int* in_sizes, int n_in,
                              void* d_out, int out_size, void* d_ws, size_t ws_size,
                              hipStream_t stream) {
    const int*   doc = (const int*)d_in[0];
    const float* emb = (const float*)d_in[1];
    const float* cw  = (const float*)d_in[2];
    const float* q2w = (const float*)d_in[3];
    const float* q2b = (const float*)d_in[4];
    float* out = (float*)d_out;
    char* ws = (char*)d_ws;

    unsigned* counts = (unsigned*)(ws + WS_COUNTS);
    double*   vq_acc = (double*)(ws + WS_VQ);
    double*   lts_acc= (double*)(ws + WS_LTS);
    double*   sumv   = (double*)(ws + WS_SUMV);
    unsigned* nflag  = (unsigned*)(ws + WS_NFLAG);
    float*    n_arr  = (float*)(ws + WS_NARR);
    float*    s_arr  = (float*)(ws + WS_SARR);
    unsigned* binc   = (unsigned*)(ws + WS_BINC);
    float*    evals  = (float*)(ws + WS_LOGITS);
    unsigned* flags  = (unsigned*)(ws + WS_FLAGS);
    double*   parts  = (double*)(ws + WS_PART);

    _Float16* b1;
    hipGetSymbolAddress((void**)&b1, HIP_SYMBOL(g_B1));

    hipMemsetAsync(ws, 0, 4096, stream);
    hipMemsetAsync(binc, 0, VOCAB * sizeof(unsigned), stream);

    hipLaunchKernelGGL(k_nsprep, dim3(128),  dim3(256), 0, stream, cw, n_arr, s_arr, b1);
    hipLaunchKernelGGL(k_main,   dim3(2048), dim3(256), 0, stream, doc, emb, cw, n_arr,
                       out, counts, binc, vq_acc, nflag, flags);
    hipLaunchKernelGGL(k_fixup,  dim3(2048), dim3(512), 0, stream, doc, emb, cw, n_arr,
                       nflag, flags, out, counts, vq_acc);
    hipLaunchKernelGGL(k_docu,   dim3(1),    dim3(512), 0, stream, counts, cw, out + OFF_DOCU);
    hipLaunchKernelGGL(k_lts,    dim3(128),  dim3(256), 0, stream, cw, n_arr, s_arr, lts_acc);
    hipLaunchKernelGGL(k_logexp, dim3(NPARTS), dim3(256), 0, stream,
                       out + OFF_DOCU, q2w, q2b, evals, parts);
    hipLaunchKernelGGL(k_sumred, dim3(1), dim3(256), 0, stream, parts, sumv);
    hipLaunchKernelGGL(k_final,  dim3((VOCAB + 255) / 256), dim3(256), 0, stream,
                       evals, sumv, binc, vq_acc, lts_acc, out);
}

// Round 11
// 555.758 us; speedup vs baseline: 2.3950x; 2.3950x over previous
//
#include <hip/hip_runtime.h>
#include <math.h>

#define N_TOK 131072
#define VOCAB 50257
#define DIM   512
#define K_CON 512
#define NPARTS 12565   // ceil(VOCAB/4)

// d_out layout (float32 elements)
#define OFF_ENC  ((size_t)0)
#define OFF_QW   ((size_t)67108864)
#define OFF_DOCU ((size_t)134217728)
#define OFF_OUT  ((size_t)134218240)
#define OFF_VQ   ((size_t)134268497)
#define OFF_LTS  ((size_t)134268498)

// ws layout (bytes)
#define WS_COUNTS 0        // 512 * u32
#define WS_VQ     2048     // double
#define WS_LTS    2056     // double
#define WS_SUMV   2072     // double
#define WS_NFLAG  2080     // u32
#define WS_NARR   4096     // 512 f32
#define WS_SARR   6144     // 512 f32
#define WS_BINC   8192     // VOCAB u32
#define WS_LOGITS 209920   // VOCAB f32 (holds exp(logit))
#define WS_FLAGS  411648   // FLAG_CAP u32  (ends 542720)
#define WS_PART   544768   // NPARTS double (ends 645288)
#define FLAG_CAP  32768

typedef __attribute__((ext_vector_type(4)))  float f32x4;
typedef __attribute__((ext_vector_type(8)))  _Float16 f16x8;
typedef __attribute__((ext_vector_type(16))) float f32x16;

// Codebook as fp16 of (512*c): frag [(s*2+hf)*512 + c] x f16x8. 512 KB.
__device__ _Float16 g_B1[32 * 2 * 512 * 8];
// Embedding table as fp16 (unscaled), row-major [VOCAB][512]. ~51.5 MB.
__device__ _Float16 g_A16[(size_t)VOCAB * DIM];
// Per-vocab-row |x|^2 (double-accumulated, rounded to f32).
__device__ float g_NW[VOCAB];

__device__ inline void gload16(const void* g, void* l) {
    __builtin_amdgcn_global_load_lds(
        (const __attribute__((address_space(1))) unsigned int*)g,
        (__attribute__((address_space(3))) unsigned int*)l, 16, 0, 0);
}

// ---------------------------------------------------------------------------
// merged: n/s arrays + codebook fp16 (512*c) prep
__global__ void k_nsprep(const float* __restrict__ cw, float* __restrict__ n_arr,
                         float* __restrict__ s_arr, _Float16* __restrict__ b1) {
    int w = threadIdx.x >> 6, lane = threadIdx.x & 63;
    int r = blockIdx.x * 4 + w;
    const float* row = cw + (size_t)r * DIM;
    {
        float4 a = *(const float4*)(row + lane * 8);
        float4 b = *(const float4*)(row + lane * 8 + 4);
        float v[8] = {a.x,a.y,a.z,a.w,b.x,b.y,b.z,b.w};
        double na = 0.0, sa = 0.0;
        #pragma unroll
        for (int e = 0; e < 8; ++e) { na += (double)v[e]*v[e]; sa += (double)v[e]; }
        for (int off = 32; off; off >>= 1) {
            na += __shfl_down(na, off);
            sa += __shfl_down(sa, off);
        }
        if (lane == 0) { n_arr[r] = (float)na; s_arr[r] = (float)sa; }
    }
    {
        int s = lane >> 1, hf = lane & 1;
        const float* p = row + s * 16 + hf * 8;
        float4 xa = *(const float4*)p;
        float4 xb = *(const float4*)(p + 4);
        float xf[8] = {xa.x,xa.y,xa.z,xa.w,xb.x,xb.y,xb.z,xb.w};
        f16x8 h8;
        #pragma unroll
        for (int e = 0; e < 8; ++e) h8[e] = (_Float16)(xf[e] * 512.0f);
        *(f16x8*)&b1[(((size_t)s * 2 + hf) * 512 + r) * 8] = h8;
    }
}

// ---------------------------------------------------------------------------
// emb -> fp16 table + per-row |x|^2 (wave per row, 4 rows per block)
__global__ void k_prepa(const float* __restrict__ emb, _Float16* __restrict__ a16,
                        float* __restrict__ nw) {
    int wv = threadIdx.x >> 6, lane = threadIdx.x & 63;
    int r = blockIdx.x * 4 + wv;
    if (r >= VOCAB) return;
    const float* row = emb + (size_t)r * DIM;
    float4 a = *(const float4*)(row + lane * 8);
    float4 b = *(const float4*)(row + lane * 8 + 4);
    float v[8] = {a.x,a.y,a.z,a.w,b.x,b.y,b.z,b.w};
    f16x8 h;
    double na = 0.0;
    #pragma unroll
    for (int e = 0; e < 8; ++e) { h[e] = (_Float16)v[e]; na += (double)v[e]*v[e]; }
    *(f16x8*)&a16[(size_t)r * DIM + lane * 8] = h;
    for (int off = 32; off; off >>= 1) na += __shfl_down(na, off);
    if (lane == 0) nw[r] = (float)na;
}

// ---------------------------------------------------------------------------
// Main: fp16 single-term MFMA distance GEMM. 512 threads = 8 waves (2
// token-groups x 4 concept-quarters). B in 3x32KB LDS ring, counted-vmcnt
// pipeline: per phase vmcnt(6) (never 0 mid-loop) -> s_barrier -> issue
// A(p+2)+STAGE(p+2) -> MFMA(p). A frags straight from fp16 table (no cvt).
__global__ __launch_bounds__(512, 2)
void k_main(const int* __restrict__ doc, const float* __restrict__ cw,
            const float* __restrict__ n_arr,
            float* __restrict__ out, unsigned* __restrict__ counts,
            unsigned* __restrict__ binc,
            double* __restrict__ vq_acc, unsigned* __restrict__ nflag,
            unsigned* __restrict__ flag_list) {
    __shared__ f16x8 bsh[3][2048];      // 96 KB triple-buffered phase tiles
    __shared__ float nsl[512];
    __shared__ float nxs[64];
    __shared__ uint4 redv[8][64];       // 8 KB
    __shared__ int docs[64];
    __shared__ int idxs[64];
    __shared__ double dred[512];        // 4 KB

    const int tid   = threadIdx.x;
    const int n0    = blockIdx.x * 64;
    const int lane  = tid & 63;
    const int wv    = tid >> 6;
    const int wm    = wv >> 2;          // token group 0/1
    const int wq    = wv & 3;           // concept quarter
    const int hv    = lane >> 5;
    const int ln31  = lane & 31;
    const int cbase = wq * 128 + ln31;

    if (tid < 64) docs[tid] = doc[n0 + tid];
    nsl[tid] = n_arr[tid];
    __syncthreads();

#define STAGE_PHASE(P, DST)                                                   \
    {                                                                         \
        const char* srcb = (const char*)g_B1 + (size_t)(P) * 32768;           \
        char* dstb = (char*)(DST);                                            \
        _Pragma("unroll")                                                     \
        for (int i = 0; i < 4; ++i)                                           \
            gload16(srcb + i * 8192 + tid * 16, dstb + i * 8192 + tid * 16);  \
    }

    const char* aptr = (const char*)(g_A16 + (size_t)docs[wm * 32 + ln31] * DIM);

    // prologue: stage phases 0,1; A(0) and A(1) to regs; nx from table
    STAGE_PHASE(0, bsh[0]);
    STAGE_PHASE(1, bsh[1]);
    f16x8 xc0 = *(const f16x8*)(aptr + (hv * 8) * 2);
    f16x8 xc1 = *(const f16x8*)(aptr + (hv * 8) * 2 + 32);
    f16x8 xn0 = *(const f16x8*)(aptr + (32 + hv * 8) * 2);
    f16x8 xn1 = *(const f16x8*)(aptr + (32 + hv * 8) * 2 + 32);
    if (tid < 64) nxs[tid] = g_NW[docs[tid]];
    __syncthreads();   // one-time full drain: stage 0/1 + A + nxs

    f32x16 acc[4];
    #pragma unroll
    for (int n = 0; n < 4; ++n) acc[n] = (f32x16)(0.0f);

    #pragma unroll
    for (int p = 0; p < 16; ++p) {
        if (p == 1) {
            __builtin_amdgcn_sched_barrier(0);
            __builtin_amdgcn_s_barrier();
            __builtin_amdgcn_sched_barrier(0);
        } else if (p >= 2) {
            __builtin_amdgcn_sched_barrier(0);
            if (p == 15) asm volatile("s_waitcnt vmcnt(0)" ::: "memory");
            else         asm volatile("s_waitcnt vmcnt(6)" ::: "memory");
            __builtin_amdgcn_sched_barrier(0);
            __builtin_amdgcn_s_barrier();
            __builtin_amdgcn_sched_barrier(0);
        }
        f16x8 na0, na1;
        bool have_next = (p + 2 < 16);
        if (have_next) {
            // A(p+2) issued BEFORE STAGE(p+2): consuming it later only forces
            // retire of loads up to here, keeping the next stage in flight.
            na0 = *(const f16x8*)(aptr + ((p + 2) * 32 + hv * 8) * 2);
            na1 = *(const f16x8*)(aptr + ((p + 2) * 32 + hv * 8) * 2 + 32);
            __builtin_amdgcn_sched_barrier(0);
            STAGE_PHASE(p + 2, bsh[(p + 2) % 3]);
            __builtin_amdgcn_sched_barrier(0);
        }
        const f16x8* bb = bsh[p % 3];
        #pragma unroll
        for (int n = 0; n < 4; ++n) {
            f16x8 b0 = bb[hv * 512 + cbase + n * 32];
            acc[n] = __builtin_amdgcn_mfma_f32_32x32x16_f16(xc0, b0, acc[n], 0, 0, 0);
        }
        #pragma unroll
        for (int n = 0; n < 4; ++n) {
            f16x8 b1 = bb[1024 + hv * 512 + cbase + n * 32];
            acc[n] = __builtin_amdgcn_mfma_f32_32x32x16_f16(xc1, b1, acc[n], 0, 0, 0);
        }
        xc0 = xn0; xc1 = xn1;
        if (have_next) { xn0 = na0; xn1 = na1; }
    }
#undef STAGE_PHASE
    __syncthreads();   // K-loop done; LDS quiesced for reduction use

    float nsv[4];
    #pragma unroll
    for (int n = 0; n < 4; ++n) nsv[n] = nsl[cbase + n * 32];

    // per-row argmin + second best; C/D: col=lane&31, row=(r&3)+8*(r>>2)+4*hv
    // acc holds S = x_h . (512 c)_h ; d = fmaf(-2^-8, S, nx+nc)
    #pragma unroll
    for (int r = 0; r < 16; ++r) {
        int tt = (r & 3) + ((r >> 2) << 3) + (hv << 2);   // 0..31 within wm
        float nxr = nxs[wm * 32 + tt];
        float v1 = INFINITY, v2 = INFINITY; int j1 = 0x7fffffff;
        #pragma unroll
        for (int n = 0; n < 4; ++n) {
            float d = fmaf(-0.00390625f, acc[n][r], nxr + nsv[n]);
            int jj = cbase + n * 32;
            if (d < v1) { v2 = v1; v1 = d; j1 = jj; }
            else if (d < v2) { v2 = d; }
        }
        #pragma unroll
        for (int off = 1; off < 32; off <<= 1) {
            float ov1 = __shfl_xor(v1, off);
            int   oj1 = __shfl_xor(j1, off);
            float ov2 = __shfl_xor(v2, off);
            v2 = fminf(fminf(v2, ov2), fmaxf(v1, ov1));
            bool take = (ov1 < v1) || (ov1 == v1 && oj1 < j1);
            if (take) { v1 = ov1; j1 = oj1; }
        }
        if (ln31 == 0)
            redv[wv][wm * 32 + tt] = make_uint4(__float_as_uint(v1), (unsigned)j1,
                                                __float_as_uint(v2), 0u);
    }
    __syncthreads();
    double myv1 = 0.0;
    if (tid < 64) {
        int g = tid >> 5;   // token group
        uint4 a = redv[g * 4][tid];
        float v1 = __uint_as_float(a.x), v2 = __uint_as_float(a.z);
        int j1 = (int)a.y;
        #pragma unroll
        for (int w = 1; w < 4; ++w) {
            uint4 b = redv[g * 4 + w][tid];
            float wv1 = __uint_as_float(b.x), wv2 = __uint_as_float(b.z);
            v2 = fminf(fminf(v2, wv2), fmaxf(v1, wv1));
            bool take = (wv1 < v1) || (wv1 == v1 && (int)b.y < j1);
            if (take) { v1 = wv1; j1 = (int)b.y; }
        }
        idxs[tid] = j1;
        atomicAdd(&counts[j1], 1u);
        atomicAdd(&binc[docs[tid]], 1u);
        myv1 = (double)v1;
        if (v2 - v1 <= 2e-6f) {           // ~8 sigma of fp16-path noise
            unsigned pq = atomicAdd(nflag, 1u);
            if (pq < FLAG_CAP) flag_list[pq] = (unsigned)(n0 + tid);
        }
    }
    dred[tid] = myv1;
    __syncthreads();

    // encodings: one-hot rows (nontemporal streaming output)
    for (int lin = tid; lin < 8192; lin += 512) {
        int t = lin >> 7, f4 = lin & 127;
        int idx = idxs[t];
        int b4 = f4 << 2;
        f32x4 v;
        v.x = (idx == b4)     ? 1.f : 0.f;
        v.y = (idx == b4 + 1) ? 1.f : 0.f;
        v.z = (idx == b4 + 2) ? 1.f : 0.f;
        v.w = (idx == b4 + 3) ? 1.f : 0.f;
        __builtin_nontemporal_store(v,
            (f32x4*)(out + OFF_ENC + ((size_t)(n0 + t) << 9) + (size_t)b4));
    }
    // quantized_words = codebook rows
    for (int lin = tid; lin < 8192; lin += 512) {
        int t = lin >> 7, f4 = lin & 127;
        f32x4 c4 = *(const f32x4*)(cw + (size_t)idxs[t] * DIM + (f4 << 2));
        __builtin_nontemporal_store(c4,
            (f32x4*)(out + OFF_QW + ((size_t)(n0 + t) << 9) + (size_t)(f4 << 2)));
    }
    // vq partial reduce (flagged tokens patched exactly by k_fixup)
    for (int st = 256; st; st >>= 1) {
        if (tid < st) dred[tid] += dred[tid + st];
        __syncthreads();
    }
    if (tid == 0) atomicAdd(vq_acc, dred[0]);
}

// ---------------------------------------------------------------------------
// Exact fp32 recompute for flagged near-tie tokens (vectorized, grid-stride).
__global__ __launch_bounds__(512)
void k_fixup(const int* __restrict__ doc, const float* __restrict__ emb,
             const float* __restrict__ cw, const float* __restrict__ n_arr,
             const float* __restrict__ nw,
             const unsigned* __restrict__ nflag, const unsigned* __restrict__ flag_list,
             float* __restrict__ out, unsigned* __restrict__ counts,
             double* __restrict__ vq_acc) {
    __shared__ float4 xs4[128];
    __shared__ int oldj_sh;
    __shared__ float vsh[512];
    __shared__ unsigned long long keys[512];

    const int tid = threadIdx.x;
    unsigned nf = *nflag;
    if (nf > FLAG_CAP) nf = FLAG_CAP;

    for (unsigned f = blockIdx.x; f < nf; f += gridDim.x) {
        int t = (int)flag_list[f];
        int dc = doc[t];
        float nxf = nw[dc];
        if (tid < 128)
            xs4[tid] = *(const float4*)(emb + (size_t)dc * DIM + tid * 4);
        if (tid == 0) oldj_sh = -1;
        __syncthreads();
        {
            float e = out[OFF_ENC + (size_t)t * 512 + tid];
            if (e == 1.0f) oldj_sh = tid;
        }
        {
            const float4* cr = (const float4*)(cw + (size_t)tid * DIM);
            float acc = 0.f;
            #pragma unroll 8
            for (int fq = 0; fq < 128; ++fq) {
                float4 c4 = cr[fq], x4 = xs4[fq];
                acc = fmaf(x4.x, c4.x, acc);
                acc = fmaf(x4.y, c4.y, acc);
                acc = fmaf(x4.z, c4.z, acc);
                acc = fmaf(x4.w, c4.w, acc);
            }
            float v = fmaf(-2.f, acc, nxf + n_arr[tid]);
            vsh[tid] = v;
            keys[tid] = (((unsigned long long)__float_as_uint(v)) << 32) | (unsigned)tid;
        }
        __syncthreads();
        for (int st = 256; st; st >>= 1) {
            if (tid < st) {
                unsigned long long o = keys[tid + st];
                if (o < keys[tid]) keys[tid] = o;
            }
            __syncthreads();
        }
        int newj = (int)(keys[0] & 0xffffffffu);
        int oldj = oldj_sh;
        if (newj != oldj) {
            if (tid == 0) {
                out[OFF_ENC + (size_t)t * 512 + oldj] = 0.0f;
                out[OFF_ENC + (size_t)t * 512 + newj] = 1.0f;
                atomicSub(&counts[oldj], 1u);
                atomicAdd(&counts[newj], 1u);
                atomicAdd(vq_acc, (double)vsh[newj] - (double)vsh[oldj]);
            }
            if (tid < 128) {
                float4 cn = *(const float4*)(cw + (size_t)newj * DIM + tid * 4);
                *(float4*)&out[OFF_QW + (size_t)t * 512 + tid * 4] = cn;
            }
        }
        __syncthreads();
    }
}

// ---------------------------------------------------------------------------
__global__ void k_docu(const unsigned* __restrict__ counts,
                       const float* __restrict__ cw, float* __restrict__ out_docu) {
    __shared__ float cnt[512];
    int tid = threadIdx.x;
    cnt[tid] = (float)counts[tid];
    __syncthreads();
    double a = 0.0;
    for (int j = 0; j < K_CON; ++j)
        a += (double)cnt[j] * (double)cw[(size_t)j * DIM + tid];
    out_docu[tid] = (float)(a * (1.0 / (double)N_TOK));
}

__global__ __launch_bounds__(256)
void k_lts(const float* __restrict__ cw, const float* __restrict__ n_arr,
           const float* __restrict__ s_arr, double* __restrict__ lts_acc) {
    __shared__ float ci[4 * 512];
    __shared__ float cjs[64 * 68];
    __shared__ double dred[256];
    const int tid = threadIdx.x;
    const int i0 = blockIdx.x * 4;
    #pragma unroll
    for (int rep = 0; rep < 2; ++rep) {
        int lin = rep * 256 + tid;
        int r = lin >> 7, fq = lin & 127;
        *(float4*)&ci[r*512 + fq*4] = *(const float4*)(cw + (size_t)(i0+r)*DIM + fq*4);
    }
    const int jj = tid & 63, ih = tid >> 6;
    const int ig = i0 + ih;
    const float ni = n_arr[ig], si = s_arr[ig];
    const float EPS = 1e-6f;
    double lsum = 0.0;
    for (int jc = 0; jc < 8; ++jc) {
        float accv = 0.f;
        for (int dc = 0; dc < 8; ++dc) {
            __syncthreads();
            #pragma unroll
            for (int rep = 0; rep < 4; ++rep) {
                int lin = rep * 256 + tid;
                int j = lin >> 4, fq = lin & 15;
                float4 v = *(const float4*)(cw + (size_t)(jc*64 + j)*DIM + dc*64 + fq*4);
                cjs[(fq*4+0)*68 + j] = v.x; cjs[(fq*4+1)*68 + j] = v.y;
                cjs[(fq*4+2)*68 + j] = v.z; cjs[(fq*4+3)*68 + j] = v.w;
            }
            __syncthreads();
            #pragma unroll 4
            for (int d = 0; d < 64; ++d)
                accv = fmaf(ci[ih*512 + dc*64 + d], cjs[d*68 + jj], accv);
        }
        int jg = jc*64 + jj;
        float ddv = ni + n_arr[jg] - 2.f*accv + 2.f*EPS*(si - s_arr[jg]) + 512.f*EPS*EPS;
        float dist = sqrtf(fmaxf(ddv, 0.f));
        lsum += (double)((ig == jg) ? dist : fmaxf(0.f, 1.f - dist));
    }
    dred[tid] = lsum;
    __syncthreads();
    for (int s = 128; s; s >>= 1) {
        if (tid < s) dred[tid] += dred[tid + s];
        __syncthreads();
    }
    if (tid == 0) atomicAdd(lts_acc, dred[0]);
}

// logits -> e = exp(logit + bias), per-block partial sums (no max: |logit| tiny)
__global__ void k_logexp(const float* __restrict__ docu, const float* __restrict__ q2w,
                         const float* __restrict__ q2b, float* __restrict__ evals,
                         double* __restrict__ parts) {
    __shared__ double esh[4];
    int wvi = threadIdx.x >> 6, lane = threadIdx.x & 63;
    int v = blockIdx.x * 4 + wvi;
    if (lane == 0) esh[wvi] = 0.0;
    if (v < VOCAB) {
        const float* wr = q2w + (size_t)v * DIM;
        float4 a = *(const float4*)(wr + lane*8);
        float4 b = *(const float4*)(wr + lane*8 + 4);
        float4 da = *(const float4*)(docu + lane*8);
        float4 db = *(const float4*)(docu + lane*8 + 4);
        float p = a.x*da.x + a.y*da.y + a.z*da.z + a.w*da.w
                + b.x*db.x + b.y*db.y + b.z*db.z + b.w*db.w;
        for (int off = 32; off; off >>= 1) p += __shfl_down(p, off);
        if (lane == 0) {
            float e = expf(p + q2b[v]);
            evals[v] = e;
            esh[wvi] = (double)e;
        }
    }
    __syncthreads();
    if (threadIdx.x == 0)
        parts[blockIdx.x] = esh[0] + esh[1] + esh[2] + esh[3];
}

__global__ void k_sumred(const double* __restrict__ parts, double* __restrict__ sumv) {
    __shared__ double red[256];
    int tid = threadIdx.x;
    double s = 0.0;
    for (int i = tid; i < NPARTS; i += 256) s += parts[i];
    red[tid] = s; __syncthreads();
    for (int st = 128; st; st >>= 1) {
        if (tid < st) red[tid] += red[tid + st];
        __syncthreads();
    }
    if (tid == 0) *sumv = red[0];
}

__global__ void k_final(const float* __restrict__ evals,
                        const double* __restrict__ sumv, const unsigned* __restrict__ binc,
                        const double* __restrict__ vq_acc, const double* __restrict__ lts_acc,
                        float* __restrict__ out) {
    int v = blockIdx.x * 256 + threadIdx.x;
    if (v < VOCAB) {
        float s = (float)(*sumv);
        float p = evals[v] / s;
        out[OFF_OUT + v] = logf(p + 1e-6f) * (float)binc[v];
    }
    if (v == 0) {
        out[OFF_VQ]  = (float)(1.25 * (*vq_acc) * (1.0 / 67108864.0));
        out[OFF_LTS] = (float)((*lts_acc) * (1.0 / 262144.0));
    }
}

// ---------------------------------------------------------------------------
extern "C" void kernel_launch(void* const* d_in, const int* in_sizes, int n_in,
                              void* d_out, int out_size, void* d_ws, size_t ws_size,
                              hipStream_t stream) {
    const int*   doc = (const int*)d_in[0];
    const float* emb = (const float*)d_in[1];
    const float* cw  = (const float*)d_in[2];
    const float* q2w = (const float*)d_in[3];
    const float* q2b = (const float*)d_in[4];
    float* out = (float*)d_out;
    char* ws = (char*)d_ws;

    unsigned* counts = (unsigned*)(ws + WS_COUNTS);
    double*   vq_acc = (double*)(ws + WS_VQ);
    double*   lts_acc= (double*)(ws + WS_LTS);
    double*   sumv   = (double*)(ws + WS_SUMV);
    unsigned* nflag  = (unsigned*)(ws + WS_NFLAG);
    float*    n_arr  = (float*)(ws + WS_NARR);
    float*    s_arr  = (float*)(ws + WS_SARR);
    unsigned* binc   = (unsigned*)(ws + WS_BINC);
    float*    evals  = (float*)(ws + WS_LOGITS);
    unsigned* flags  = (unsigned*)(ws + WS_FLAGS);
    double*   parts  = (double*)(ws + WS_PART);

    _Float16* b1;  hipGetSymbolAddress((void**)&b1,  HIP_SYMBOL(g_B1));
    _Float16* a16; hipGetSymbolAddress((void**)&a16, HIP_SYMBOL(g_A16));
    float*    nw;  hipGetSymbolAddress((void**)&nw,  HIP_SYMBOL(g_NW));

    hipMemsetAsync(ws, 0, 4096, stream);
    hipMemsetAsync(binc, 0, VOCAB * sizeof(unsigned), stream);

    hipLaunchKernelGGL(k_nsprep, dim3(128),   dim3(256), 0, stream, cw, n_arr, s_arr, b1);
    hipLaunchKernelGGL(k_prepa,  dim3(NPARTS), dim3(256), 0, stream, emb, a16, nw);
    hipLaunchKernelGGL(k_main,   dim3(2048),  dim3(512), 0, stream, doc, cw, n_arr,
                       out, counts, binc, vq_acc, nflag, flags);
    hipLaunchKernelGGL(k_fixup,  dim3(2048),  dim3(512), 0, stream, doc, emb, cw, n_arr,
                       nw, nflag, flags, out, counts, vq_acc);
    hipLaunchKernelGGL(k_docu,   dim3(1),     dim3(512), 0, stream, counts, cw, out + OFF_DOCU);
    hipLaunchKernelGGL(k_lts,    dim3(128),   dim3(256), 0, stream, cw, n_arr, s_arr, lts_acc);
    hipLaunchKernelGGL(k_logexp, dim3(NPARTS), dim3(256), 0, stream,
                       out + OFF_DOCU, q2w, q2b, evals, parts);
    hipLaunchKernelGGL(k_sumred, dim3(1), dim3(256), 0, stream, parts, sumv);
    hipLaunchKernelGGL(k_final,  dim3((VOCAB + 255) / 256), dim3(256), 0, stream,
                       evals, sumv, binc, vq_acc, lts_acc, out);
}

// Round 12
// 460.565 us; speedup vs baseline: 2.8900x; 1.2067x over previous
//
#include <hip/hip_runtime.h>
#include <math.h>

#define N_TOK 131072
#define VOCAB 50257
#define DIM   512
#define K_CON 512
#define NPARTS 12565   // ceil(VOCAB/4)

// d_out layout (float32 elements)
#define OFF_ENC  ((size_t)0)
#define OFF_QW   ((size_t)67108864)
#define OFF_DOCU ((size_t)134217728)
#define OFF_OUT  ((size_t)134218240)
#define OFF_VQ   ((size_t)134268497)
#define OFF_LTS  ((size_t)134268498)

// ws layout (bytes)
#define WS_COUNTS 0        // 512 * u32
#define WS_VQ     2048     // double
#define WS_LTS    2056     // double
#define WS_SUMV   2072     // double
#define WS_NFLAG  2080     // u32
#define WS_NARR   4096     // 512 f32
#define WS_SARR   6144     // 512 f32
#define WS_BINC   8192     // VOCAB u32
#define WS_LOGITS 209920   // VOCAB f32 (holds exp(logit))
#define WS_FLAGS  411648   // FLAG_CAP u32  (ends 542720)
#define WS_PART   544768   // NPARTS double (ends 645288)
#define FLAG_CAP  32768

typedef __attribute__((ext_vector_type(4)))  float f32x4;
typedef __attribute__((ext_vector_type(8)))  _Float16 f16x8;
typedef __attribute__((ext_vector_type(16))) float f32x16;

// Codebook as fp16 of (512*c): frag [(s*2+hf)*512 + c] x f16x8. 512 KB.
// K-step tile s = 16 KB at byte offset s*16384 (first 8 KB hf=0, then hf=1).
__device__ _Float16 g_B1[32 * 2 * 512 * 8];
// Embedding table as fp16 (unscaled), row-major [VOCAB][512]. ~51.5 MB.
__device__ _Float16 g_A16[(size_t)VOCAB * DIM];
// Per-vocab-row |x|^2 (double-accumulated, rounded to f32).
__device__ float g_NW[VOCAB];

__device__ inline void gload16(const void* g, void* l) {
    __builtin_amdgcn_global_load_lds(
        (const __attribute__((address_space(1))) unsigned int*)g,
        (__attribute__((address_space(3))) unsigned int*)l, 16, 0, 0);
}

// ---------------------------------------------------------------------------
// merged: n/s arrays + codebook fp16 (512*c) prep + ws scalar zeroing
__global__ void k_nsprep(const float* __restrict__ cw, float* __restrict__ n_arr,
                         float* __restrict__ s_arr, _Float16* __restrict__ b1,
                         uint4* __restrict__ wz) {
    if (blockIdx.x == 0) {
        uint4 z; z.x = 0u; z.y = 0u; z.z = 0u; z.w = 0u;
        wz[threadIdx.x] = z;          // 256 * 16 B = 4 KB scalar region
    }
    int w = threadIdx.x >> 6, lane = threadIdx.x & 63;
    int r = blockIdx.x * 4 + w;
    const float* row = cw + (size_t)r * DIM;
    {
        float4 a = *(const float4*)(row + lane * 8);
        float4 b = *(const float4*)(row + lane * 8 + 4);
        float v[8] = {a.x,a.y,a.z,a.w,b.x,b.y,b.z,b.w};
        double na = 0.0, sa = 0.0;
        #pragma unroll
        for (int e = 0; e < 8; ++e) { na += (double)v[e]*v[e]; sa += (double)v[e]; }
        for (int off = 32; off; off >>= 1) {
            na += __shfl_down(na, off);
            sa += __shfl_down(sa, off);
        }
        if (lane == 0) { n_arr[r] = (float)na; s_arr[r] = (float)sa; }
    }
    {
        int s = lane >> 1, hf = lane & 1;
        const float* p = row + s * 16 + hf * 8;
        float4 xa = *(const float4*)p;
        float4 xb = *(const float4*)(p + 4);
        float xf[8] = {xa.x,xa.y,xa.z,xa.w,xb.x,xb.y,xb.z,xb.w};
        f16x8 h8;
        #pragma unroll
        for (int e = 0; e < 8; ++e) h8[e] = (_Float16)(xf[e] * 512.0f);
        *(f16x8*)&b1[(((size_t)s * 2 + hf) * 512 + r) * 8] = h8;
    }
}

// ---------------------------------------------------------------------------
// emb -> fp16 table + per-row |x|^2 + binc zeroing (covers all VOCAB rows)
__global__ void k_prepa(const float* __restrict__ emb, _Float16* __restrict__ a16,
                        float* __restrict__ nw, unsigned* __restrict__ binc) {
    int wv = threadIdx.x >> 6, lane = threadIdx.x & 63;
    int r = blockIdx.x * 4 + wv;
    if (r >= VOCAB) return;
    const float* row = emb + (size_t)r * DIM;
    float4 a = *(const float4*)(row + lane * 8);
    float4 b = *(const float4*)(row + lane * 8 + 4);
    float v[8] = {a.x,a.y,a.z,a.w,b.x,b.y,b.z,b.w};
    f16x8 h;
    double na = 0.0;
    #pragma unroll
    for (int e = 0; e < 8; ++e) { h[e] = (_Float16)v[e]; na += (double)v[e]*v[e]; }
    *(f16x8*)&a16[(size_t)r * DIM + lane * 8] = h;
    for (int off = 32; off; off >>= 1) na += __shfl_down(na, off);
    if (lane == 0) { nw[r] = (float)na; binc[r] = 0u; }
}

// ---------------------------------------------------------------------------
// Main: fp16 single-term MFMA distance GEMM. 512 threads = 8 waves (2
// token-groups x 4 concept-quarters). B in 4 x 16 KB LDS ring (BK=16, 32
// phases), counted-vmcnt pipeline: stage(p+3) issued at phase p; boundary
// entering p waits vmcnt(6) (tail: 3, 0) -> s_barrier. Never drains the
// in-flight window mid-loop. 2 blocks/CU (LDS ~79 KB).
__global__ __launch_bounds__(512, 4)
void k_main(const int* __restrict__ doc, const float* __restrict__ cw,
            const float* __restrict__ n_arr,
            float* __restrict__ out, unsigned* __restrict__ counts,
            unsigned* __restrict__ binc,
            double* __restrict__ vq_acc, unsigned* __restrict__ nflag,
            unsigned* __restrict__ flag_list) {
    __shared__ f16x8 bsh[4][1024];      // 64 KB ring of K-step tiles
    __shared__ float nsl[512];
    __shared__ float nxs[64];
    __shared__ uint4 redv[8][64];       // 8 KB
    __shared__ int docs[64];
    __shared__ int idxs[64];
    __shared__ double dred[512];        // 4 KB

    const int tid   = threadIdx.x;
    const int n0    = blockIdx.x * 64;
    const int lane  = tid & 63;
    const int wv    = tid >> 6;
    const int wm    = wv >> 2;          // token group 0/1
    const int wq    = wv & 3;           // concept quarter
    const int hv    = lane >> 5;
    const int ln31  = lane & 31;
    const int cbase = wq * 128 + ln31;

    if (tid < 64) docs[tid] = doc[n0 + tid];
    nsl[tid] = n_arr[tid];
    __syncthreads();

#define STAGE16(P, DST)                                                       \
    {                                                                         \
        const char* srcb = (const char*)g_B1 + (size_t)(P) * 16384;           \
        char* dstb = (char*)(DST);                                            \
        gload16(srcb + tid * 16, dstb + tid * 16);                            \
        gload16(srcb + 8192 + tid * 16, dstb + 8192 + tid * 16);              \
    }

    const char* aptr = (const char*)(g_A16 + (size_t)docs[wm * 32 + ln31] * DIM);

    // prologue: stage steps 0..2; A(0..2) to regs; nx from table
    STAGE16(0, bsh[0]);
    STAGE16(1, bsh[1]);
    STAGE16(2, bsh[2]);
    f16x8 x0 = *(const f16x8*)(aptr + (hv * 8) * 2);
    f16x8 x1 = *(const f16x8*)(aptr + (16 + hv * 8) * 2);
    f16x8 x2 = *(const f16x8*)(aptr + (32 + hv * 8) * 2);
    if (tid < 64) nxs[tid] = g_NW[docs[tid]];
    __syncthreads();   // one-time full drain: stages 0-2 + A + nxs

    f32x16 acc[4];
    #pragma unroll
    for (int n = 0; n < 4; ++n) acc[n] = (f32x16)(0.0f);

    #pragma unroll
    for (int p = 0; p < 32; ++p) {
        if (p >= 1) {
            __builtin_amdgcn_sched_barrier(0);
            if (p <= 29)      asm volatile("s_waitcnt vmcnt(6)" ::: "memory");
            else if (p == 30) asm volatile("s_waitcnt vmcnt(3)" ::: "memory");
            else              asm volatile("s_waitcnt vmcnt(0)" ::: "memory");
            __builtin_amdgcn_sched_barrier(0);
            __builtin_amdgcn_s_barrier();
            __builtin_amdgcn_sched_barrier(0);
        }
        f16x8 na = x2;
        if (p + 3 < 32) {
            // A(p+3) then STAGE(p+3) -> buf (p+3)&3 (= buf (p-1)&3, whose
            // readers all passed the barrier above). 3 vmem ops per phase.
            na = *(const f16x8*)(aptr + ((p + 3) * 16 + hv * 8) * 2);
            __builtin_amdgcn_sched_barrier(0);
            STAGE16(p + 3, bsh[(p + 3) & 3]);
            __builtin_amdgcn_sched_barrier(0);
        }
        const f16x8* bb = bsh[p & 3];
        #pragma unroll
        for (int n = 0; n < 4; ++n) {
            f16x8 b = bb[hv * 512 + cbase + n * 32];
            acc[n] = __builtin_amdgcn_mfma_f32_32x32x16_f16(x0, b, acc[n], 0, 0, 0);
        }
        x0 = x1; x1 = x2; x2 = na;
    }
#undef STAGE16
    __syncthreads();   // K-loop done

    float nsv[4];
    #pragma unroll
    for (int n = 0; n < 4; ++n) nsv[n] = nsl[cbase + n * 32];

    // per-row argmin + second best; C/D: col=lane&31, row=(r&3)+8*(r>>2)+4*hv
    // acc holds S = x_h . (512 c)_h ; d = fmaf(-2^-8, S, nx+nc)
    #pragma unroll
    for (int r = 0; r < 16; ++r) {
        int tt = (r & 3) + ((r >> 2) << 3) + (hv << 2);   // 0..31 within wm
        float nxr = nxs[wm * 32 + tt];
        float v1 = INFINITY, v2 = INFINITY; int j1 = 0x7fffffff;
        #pragma unroll
        for (int n = 0; n < 4; ++n) {
            float d = fmaf(-0.00390625f, acc[n][r], nxr + nsv[n]);
            int jj = cbase + n * 32;
            if (d < v1) { v2 = v1; v1 = d; j1 = jj; }
            else if (d < v2) { v2 = d; }
        }
        #pragma unroll
        for (int off = 1; off < 32; off <<= 1) {
            float ov1 = __shfl_xor(v1, off);
            int   oj1 = __shfl_xor(j1, off);
            float ov2 = __shfl_xor(v2, off);
            v2 = fminf(fminf(v2, ov2), fmaxf(v1, ov1));
            bool take = (ov1 < v1) || (ov1 == v1 && oj1 < j1);
            if (take) { v1 = ov1; j1 = oj1; }
        }
        if (ln31 == 0)
            redv[wv][wm * 32 + tt] = make_uint4(__float_as_uint(v1), (unsigned)j1,
                                                __float_as_uint(v2), 0u);
    }
    __syncthreads();
    double myv1 = 0.0;
    if (tid < 64) {
        int g = tid >> 5;   // token group
        uint4 a = redv[g * 4][tid];
        float v1 = __uint_as_float(a.x), v2 = __uint_as_float(a.z);
        int j1 = (int)a.y;
        #pragma unroll
        for (int w = 1; w < 4; ++w) {
            uint4 b = redv[g * 4 + w][tid];
            float wv1 = __uint_as_float(b.x), wv2 = __uint_as_float(b.z);
            v2 = fminf(fminf(v2, wv2), fmaxf(v1, wv1));
            bool take = (wv1 < v1) || (wv1 == v1 && (int)b.y < j1);
            if (take) { v1 = wv1; j1 = (int)b.y; }
        }
        idxs[tid] = j1;
        atomicAdd(&counts[j1], 1u);
        atomicAdd(&binc[docs[tid]], 1u);
        myv1 = (double)v1;
        if (v2 - v1 <= 2e-6f) {           // ~8 sigma of fp16-path noise
            unsigned pq = atomicAdd(nflag, 1u);
            if (pq < FLAG_CAP) flag_list[pq] = (unsigned)(n0 + tid);
        }
    }
    dred[tid] = myv1;
    __syncthreads();

    // encodings: one-hot rows (nontemporal streaming output)
    for (int lin = tid; lin < 8192; lin += 512) {
        int t = lin >> 7, f4 = lin & 127;
        int idx = idxs[t];
        int b4 = f4 << 2;
        f32x4 v;
        v.x = (idx == b4)     ? 1.f : 0.f;
        v.y = (idx == b4 + 1) ? 1.f : 0.f;
        v.z = (idx == b4 + 2) ? 1.f : 0.f;
        v.w = (idx == b4 + 3) ? 1.f : 0.f;
        __builtin_nontemporal_store(v,
            (f32x4*)(out + OFF_ENC + ((size_t)(n0 + t) << 9) + (size_t)b4));
    }
    // quantized_words = codebook rows
    for (int lin = tid; lin < 8192; lin += 512) {
        int t = lin >> 7, f4 = lin & 127;
        f32x4 c4 = *(const f32x4*)(cw + (size_t)idxs[t] * DIM + (f4 << 2));
        __builtin_nontemporal_store(c4,
            (f32x4*)(out + OFF_QW + ((size_t)(n0 + t) << 9) + (size_t)(f4 << 2)));
    }
    // vq partial reduce (flagged tokens patched exactly by k_fixup)
    for (int st = 256; st; st >>= 1) {
        if (tid < st) dred[tid] += dred[tid + st];
        __syncthreads();
    }
    if (tid == 0) atomicAdd(vq_acc, dred[0]);
}

// ---------------------------------------------------------------------------
// Exact fp32 recompute for flagged near-tie tokens (vectorized, grid-stride).
__global__ __launch_bounds__(512)
void k_fixup(const int* __restrict__ doc, const float* __restrict__ emb,
             const float* __restrict__ cw, const float* __restrict__ n_arr,
             const float* __restrict__ nw,
             const unsigned* __restrict__ nflag, const unsigned* __restrict__ flag_list,
             float* __restrict__ out, unsigned* __restrict__ counts,
             double* __restrict__ vq_acc) {
    __shared__ float4 xs4[128];
    __shared__ int oldj_sh;
    __shared__ float vsh[512];
    __shared__ unsigned long long keys[512];

    const int tid = threadIdx.x;
    unsigned nf = *nflag;
    if (nf > FLAG_CAP) nf = FLAG_CAP;

    for (unsigned f = blockIdx.x; f < nf; f += gridDim.x) {
        int t = (int)flag_list[f];
        int dc = doc[t];
        float nxf = nw[dc];
        if (tid < 128)
            xs4[tid] = *(const float4*)(emb + (size_t)dc * DIM + tid * 4);
        if (tid == 0) oldj_sh = -1;
        __syncthreads();
        {
            float e = out[OFF_ENC + (size_t)t * 512 + tid];
            if (e == 1.0f) oldj_sh = tid;
        }
        {
            const float4* cr = (const float4*)(cw + (size_t)tid * DIM);
            float acc = 0.f;
            #pragma unroll 8
            for (int fq = 0; fq < 128; ++fq) {
                float4 c4 = cr[fq], x4 = xs4[fq];
                acc = fmaf(x4.x, c4.x, acc);
                acc = fmaf(x4.y, c4.y, acc);
                acc = fmaf(x4.z, c4.z, acc);
                acc = fmaf(x4.w, c4.w, acc);
            }
            float v = fmaf(-2.f, acc, nxf + n_arr[tid]);
            vsh[tid] = v;
            keys[tid] = (((unsigned long long)__float_as_uint(v)) << 32) | (unsigned)tid;
        }
        __syncthreads();
        for (int st = 256; st; st >>= 1) {
            if (tid < st) {
                unsigned long long o = keys[tid + st];
                if (o < keys[tid]) keys[tid] = o;
            }
            __syncthreads();
        }
        int newj = (int)(keys[0] & 0xffffffffu);
        int oldj = oldj_sh;
        if (newj != oldj) {
            if (tid == 0) {
                out[OFF_ENC + (size_t)t * 512 + oldj] = 0.0f;
                out[OFF_ENC + (size_t)t * 512 + newj] = 1.0f;
                atomicSub(&counts[oldj], 1u);
                atomicAdd(&counts[newj], 1u);
                atomicAdd(vq_acc, (double)vsh[newj] - (double)vsh[oldj]);
            }
            if (tid < 128) {
                float4 cn = *(const float4*)(cw + (size_t)newj * DIM + tid * 4);
                *(float4*)&out[OFF_QW + (size_t)t * 512 + tid * 4] = cn;
            }
        }
        __syncthreads();
    }
}

// ---------------------------------------------------------------------------
__global__ void k_docu(const unsigned* __restrict__ counts,
                       const float* __restrict__ cw, float* __restrict__ out_docu) {
    __shared__ float cnt[512];
    int tid = threadIdx.x;
    cnt[tid] = (float)counts[tid];
    __syncthreads();
    double a = 0.0;
    for (int j = 0; j < K_CON; ++j)
        a += (double)cnt[j] * (double)cw[(size_t)j * DIM + tid];
    out_docu[tid] = (float)(a * (1.0 / (double)N_TOK));
}

__global__ __launch_bounds__(256)
void k_lts(const float* __restrict__ cw, const float* __restrict__ n_arr,
           const float* __restrict__ s_arr, double* __restrict__ lts_acc) {
    __shared__ float ci[4 * 512];
    __shared__ float cjs[64 * 68];
    __shared__ double dred[256];
    const int tid = threadIdx.x;
    const int i0 = blockIdx.x * 4;
    #pragma unroll
    for (int rep = 0; rep < 2; ++rep) {
        int lin = rep * 256 + tid;
        int r = lin >> 7, fq = lin & 127;
        *(float4*)&ci[r*512 + fq*4] = *(const float4*)(cw + (size_t)(i0+r)*DIM + fq*4);
    }
    const int jj = tid & 63, ih = tid >> 6;
    const int ig = i0 + ih;
    const float ni = n_arr[ig], si = s_arr[ig];
    const float EPS = 1e-6f;
    double lsum = 0.0;
    for (int jc = 0; jc < 8; ++jc) {
        float accv = 0.f;
        for (int dc = 0; dc < 8; ++dc) {
            __syncthreads();
            #pragma unroll
            for (int rep = 0; rep < 4; ++rep) {
                int lin = rep * 256 + tid;
                int j = lin >> 4, fq = lin & 15;
                float4 v = *(const float4*)(cw + (size_t)(jc*64 + j)*DIM + dc*64 + fq*4);
                cjs[(fq*4+0)*68 + j] = v.x; cjs[(fq*4+1)*68 + j] = v.y;
                cjs[(fq*4+2)*68 + j] = v.z; cjs[(fq*4+3)*68 + j] = v.w;
            }
            __syncthreads();
            #pragma unroll 4
            for (int d = 0; d < 64; ++d)
                accv = fmaf(ci[ih*512 + dc*64 + d], cjs[d*68 + jj], accv);
        }
        int jg = jc*64 + jj;
        float ddv = ni + n_arr[jg] - 2.f*accv + 2.f*EPS*(si - s_arr[jg]) + 512.f*EPS*EPS;
        float dist = sqrtf(fmaxf(ddv, 0.f));
        lsum += (double)((ig == jg) ? dist : fmaxf(0.f, 1.f - dist));
    }
    dred[tid] = lsum;
    __syncthreads();
    for (int s = 128; s; s >>= 1) {
        if (tid < s) dred[tid] += dred[tid + s];
        __syncthreads();
    }
    if (tid == 0) atomicAdd(lts_acc, dred[0]);
}

// logits -> e = exp(logit + bias), per-block partial sums (no max: |logit| tiny)
__global__ void k_logexp(const float* __restrict__ docu, const float* __restrict__ q2w,
                         const float* __restrict__ q2b, float* __restrict__ evals,
                         double* __restrict__ parts) {
    __shared__ double esh[4];
    int wvi = threadIdx.x >> 6, lane = threadIdx.x & 63;
    int v = blockIdx.x * 4 + wvi;
    if (lane == 0) esh[wvi] = 0.0;
    if (v < VOCAB) {
        const float* wr = q2w + (size_t)v * DIM;
        float4 a = *(const float4*)(wr + lane*8);
        float4 b = *(const float4*)(wr + lane*8 + 4);
        float4 da = *(const float4*)(docu + lane*8);
        float4 db = *(const float4*)(docu + lane*8 + 4);
        float p = a.x*da.x + a.y*da.y + a.z*da.z + a.w*da.w
                + b.x*db.x + b.y*db.y + b.z*db.z + b.w*db.w;
        for (int off = 32; off; off >>= 1) p += __shfl_down(p, off);
        if (lane == 0) {
            float e = expf(p + q2b[v]);
            evals[v] = e;
            esh[wvi] = (double)e;
        }
    }
    __syncthreads();
    if (threadIdx.x == 0)
        parts[blockIdx.x] = esh[0] + esh[1] + esh[2] + esh[3];
}

__global__ void k_sumred(const double* __restrict__ parts, double* __restrict__ sumv) {
    __shared__ double red[256];
    int tid = threadIdx.x;
    double s = 0.0;
    for (int i = tid; i < NPARTS; i += 256) s += parts[i];
    red[tid] = s; __syncthreads();
    for (int st = 128; st; st >>= 1) {
        if (tid < st) red[tid] += red[tid + st];
        __syncthreads();
    }
    if (tid == 0) *sumv = red[0];
}

__global__ void k_final(const float* __restrict__ evals,
                        const double* __restrict__ sumv, const unsigned* __restrict__ binc,
                        const double* __restrict__ vq_acc, const double* __restrict__ lts_acc,
                        float* __restrict__ out) {
    int v = blockIdx.x * 256 + threadIdx.x;
    if (v < VOCAB) {
        float s = (float)(*sumv);
        float p = evals[v] / s;
        out[OFF_OUT + v] = logf(p + 1e-6f) * (float)binc[v];
    }
    if (v == 0) {
        out[OFF_VQ]  = (float)(1.25 * (*vq_acc) * (1.0 / 67108864.0));
        out[OFF_LTS] = (float)((*lts_acc) * (1.0 / 262144.0));
    }
}

// ---------------------------------------------------------------------------
extern "C" void kernel_launch(void* const* d_in, const int* in_sizes, int n_in,
                              void* d_out, int out_size, void* d_ws, size_t ws_size,
                              hipStream_t stream) {
    const int*   doc = (const int*)d_in[0];
    const float* emb = (const float*)d_in[1];
    const float* cw  = (const float*)d_in[2];
    const float* q2w = (const float*)d_in[3];
    const float* q2b = (const float*)d_in[4];
    float* out = (float*)d_out;
    char* ws = (char*)d_ws;

    unsigned* counts = (unsigned*)(ws + WS_COUNTS);
    double*   vq_acc = (double*)(ws + WS_VQ);
    double*   lts_acc= (double*)(ws + WS_LTS);
    double*   sumv   = (double*)(ws + WS_SUMV);
    unsigned* nflag  = (unsigned*)(ws + WS_NFLAG);
    float*    n_arr  = (float*)(ws + WS_NARR);
    float*    s_arr  = (float*)(ws + WS_SARR);
    unsigned* binc   = (unsigned*)(ws + WS_BINC);
    float*    evals  = (float*)(ws + WS_LOGITS);
    unsigned* flags  = (unsigned*)(ws + WS_FLAGS);
    double*   parts  = (double*)(ws + WS_PART);

    _Float16* b1;  hipGetSymbolAddress((void**)&b1,  HIP_SYMBOL(g_B1));
    _Float16* a16; hipGetSymbolAddress((void**)&a16, HIP_SYMBOL(g_A16));
    float*    nw;  hipGetSymbolAddress((void**)&nw,  HIP_SYMBOL(g_NW));

    // no hipMemsetAsync: scalars zeroed by k_nsprep block 0, binc by k_prepa

    hipLaunchKernelGGL(k_nsprep, dim3(128),   dim3(256), 0, stream, cw, n_arr, s_arr,
                       b1, (uint4*)ws);
    hipLaunchKernelGGL(k_prepa,  dim3(NPARTS), dim3(256), 0, stream, emb, a16, nw, binc);
    hipLaunchKernelGGL(k_main,   dim3(2048),  dim3(512), 0, stream, doc, cw, n_arr,
                       out, counts, binc, vq_acc, nflag, flags);
    hipLaunchKernelGGL(k_fixup,  dim3(2048),  dim3(512), 0, stream, doc, emb, cw, n_arr,
                       nw, nflag, flags, out, counts, vq_acc);
    hipLaunchKernelGGL(k_docu,   dim3(1),     dim3(512), 0, stream, counts, cw, out + OFF_DOCU);
    hipLaunchKernelGGL(k_lts,    dim3(128),   dim3(256), 0, stream, cw, n_arr, s_arr, lts_acc);
    hipLaunchKernelGGL(k_logexp, dim3(NPARTS), dim3(256), 0, stream,
                       out + OFF_DOCU, q2w, q2b, evals, parts);
    hipLaunchKernelGGL(k_sumred, dim3(1), dim3(256), 0, stream, parts, sumv);
    hipLaunchKernelGGL(k_final,  dim3((VOCAB + 255) / 256), dim3(256), 0, stream,
                       evals, sumv, binc, vq_acc, lts_acc, out);
}